// Round 2
// 1351.615 us; speedup vs baseline: 1.1898x; 1.1898x over previous
//
#include <hip/hip_runtime.h>

#define B_ 2
#define S_ 2048
#define H_ 4096
#define NH_ 32
#define HD_ 128
#define LOG2E 1.44269504088896340736f

typedef unsigned short u16;
typedef __bf16 bf16x8 __attribute__((ext_vector_type(8)));
typedef float floatx4 __attribute__((ext_vector_type(4)));

__device__ __forceinline__ u16 f2bf(float f) {
  union { float f; unsigned u; } v;
  v.f = f;
  unsigned r = v.u + 0x7FFFu + ((v.u >> 16) & 1u);
  return (u16)(r >> 16);
}

// async global->LDS DMA, 16B per lane; LDS dest = wave-uniform base + lane*16
__device__ __forceinline__ void dma16(const u16* g, u16* l) {
  __builtin_amdgcn_global_load_lds(
      (const __attribute__((address_space(1))) void*)g,
      (__attribute__((address_space(3))) void*)l, 16, 0, 0);
}

// ---------------- cast fp32 -> bf16, vectorized ----------------
__global__ __launch_bounds__(256) void cast_f32_bf16(const float* __restrict__ in,
                                                     u16* __restrict__ out, int n4) {
  int i = blockIdx.x * 256 + threadIdx.x;
  if (i >= n4) return;
  float4 f = reinterpret_cast<const float4*>(in)[i];
  ushort4 o;
  o.x = f2bf(f.x); o.y = f2bf(f.y); o.z = f2bf(f.z); o.w = f2bf(f.w);
  reinterpret_cast<ushort4*>(out)[i] = o;
}

// ---------------- GEMM: C[m][n] = sum_k A[m][k]*B[n][k] (both K-contiguous)
// 256x256 tile, BK=64, 512 threads = 8 waves (2M x 4N), each wave 128x64 out.
// 8-phase schedule (2 K-tiles / iteration), counted vmcnt(6) at phases 4 & 8
// only (never drained to 0 in the loop). LDS 128 KiB = 2 buffers x (A,B) x
// 2 halves of 128x64 bf16. Staging via global_load_lds width=16 into linear
// LDS; bank-conflict-free via chunk XOR swizzle applied to the per-lane
// GLOBAL source address and to the ds_read address (slot = chunk ^ (row&7)).
// Trailing prefetches wrap k via (kk & (K-1)): data never consumed, but all
// generated addresses stay strictly inside the operand buffers (no OOB).
#define MM(d, a_, b_) d = __builtin_amdgcn_mfma_f32_16x16x32_bf16(a_, b_, d, 0, 0, 0)
#define BARX() do { __builtin_amdgcn_s_barrier(); __builtin_amdgcn_sched_barrier(0); } while (0)
#define LGK0() do { asm volatile("s_waitcnt lgkmcnt(0)" ::: "memory"); __builtin_amdgcn_sched_barrier(0); } while (0)
#define VMC6() do { asm volatile("s_waitcnt vmcnt(6)" ::: "memory"); } while (0)
#define PRIO1() __builtin_amdgcn_s_setprio(1)
#define PRIO0() __builtin_amdgcn_s_setprio(0)

// stage one 128x64 half-tile (2 x global_load_lds per thread)
#define STGA(b, h, kk)                                                      \
  do {                                                                      \
    const u16* _g = pA + ((h) ? rh : (size_t)0) + (size_t)((kk) & kmsk);    \
    dma16(_g, &sA[b][h][wave * 512]);                                       \
    dma16(_g + ro1, &sA[b][h][4096 + wave * 512]);                          \
  } while (0)
#define STGB(b, h, kk)                                                      \
  do {                                                                      \
    const u16* _g = pB + ((h) ? rh : (size_t)0) + (size_t)((kk) & kmsk);    \
    dma16(_g, &sB[b][h][wave * 512]);                                       \
    dma16(_g + ro1, &sB[b][h][4096 + wave * 512]);                          \
  } while (0)

// one K-tile = 4 phases. Reads: A m0-1 + B all @p1, A m2-3 @p2, A m4-7 @p3.
// Each half of this buffer is thus free exactly one phase before the stage
// that overwrites it (ST2->B0 after p1, ST3->B1 after p1, ST4->A0 after p3,
// next HALF's ST1->A1 after p3). vmcnt(6) at phase 4 = 3 half-tiles in flight.
#define HALF(b, ST1, ST2, ST3, ST4)                                         \
  {                                                                         \
    const char* baA = (const char*)&sA[b][wm][0];                           \
    const char* baB = (const char*)&sB[b][wn >> 1][(wn & 1) * 4096];        \
    bf16x8 x00 = *(const bf16x8*)(baA + 0 * 2048 + fo0);                    \
    bf16x8 x01 = *(const bf16x8*)(baA + 0 * 2048 + fo1);                    \
    bf16x8 x10 = *(const bf16x8*)(baA + 1 * 2048 + fo0);                    \
    bf16x8 x11 = *(const bf16x8*)(baA + 1 * 2048 + fo1);                    \
    bf16x8 q00 = *(const bf16x8*)(baB + 0 * 2048 + fo0);                    \
    bf16x8 q01 = *(const bf16x8*)(baB + 0 * 2048 + fo1);                    \
    bf16x8 q10 = *(const bf16x8*)(baB + 1 * 2048 + fo0);                    \
    bf16x8 q11 = *(const bf16x8*)(baB + 1 * 2048 + fo1);                    \
    bf16x8 q20 = *(const bf16x8*)(baB + 2 * 2048 + fo0);                    \
    bf16x8 q21 = *(const bf16x8*)(baB + 2 * 2048 + fo1);                    \
    bf16x8 q30 = *(const bf16x8*)(baB + 3 * 2048 + fo0);                    \
    bf16x8 q31 = *(const bf16x8*)(baB + 3 * 2048 + fo1);                    \
    ST1;                                                                    \
    BARX(); LGK0(); PRIO1();                                                \
    MM(acc[0][0], x00, q00); MM(acc[0][0], x01, q01);                       \
    MM(acc[0][1], x00, q10); MM(acc[0][1], x01, q11);                       \
    MM(acc[0][2], x00, q20); MM(acc[0][2], x01, q21);                       \
    MM(acc[0][3], x00, q30); MM(acc[0][3], x01, q31);                       \
    MM(acc[1][0], x10, q00); MM(acc[1][0], x11, q01);                       \
    MM(acc[1][1], x10, q10); MM(acc[1][1], x11, q11);                       \
    MM(acc[1][2], x10, q20); MM(acc[1][2], x11, q21);                       \
    MM(acc[1][3], x10, q30); MM(acc[1][3], x11, q31);                       \
    PRIO0(); BARX();                                                        \
    bf16x8 y00 = *(const bf16x8*)(baA + 2 * 2048 + fo0);                    \
    bf16x8 y01 = *(const bf16x8*)(baA + 2 * 2048 + fo1);                    \
    bf16x8 y10 = *(const bf16x8*)(baA + 3 * 2048 + fo0);                    \
    bf16x8 y11 = *(const bf16x8*)(baA + 3 * 2048 + fo1);                    \
    ST2;                                                                    \
    BARX(); LGK0(); PRIO1();                                                \
    MM(acc[2][0], y00, q00); MM(acc[2][0], y01, q01);                       \
    MM(acc[2][1], y00, q10); MM(acc[2][1], y01, q11);                       \
    MM(acc[2][2], y00, q20); MM(acc[2][2], y01, q21);                       \
    MM(acc[2][3], y00, q30); MM(acc[2][3], y01, q31);                       \
    MM(acc[3][0], y10, q00); MM(acc[3][0], y11, q01);                       \
    MM(acc[3][1], y10, q10); MM(acc[3][1], y11, q11);                       \
    MM(acc[3][2], y10, q20); MM(acc[3][2], y11, q21);                       \
    MM(acc[3][3], y10, q30); MM(acc[3][3], y11, q31);                       \
    PRIO0(); BARX();                                                        \
    bf16x8 z00 = *(const bf16x8*)(baA + 4 * 2048 + fo0);                    \
    bf16x8 z01 = *(const bf16x8*)(baA + 4 * 2048 + fo1);                    \
    bf16x8 z10 = *(const bf16x8*)(baA + 5 * 2048 + fo0);                    \
    bf16x8 z11 = *(const bf16x8*)(baA + 5 * 2048 + fo1);                    \
    bf16x8 w00 = *(const bf16x8*)(baA + 6 * 2048 + fo0);                    \
    bf16x8 w01 = *(const bf16x8*)(baA + 6 * 2048 + fo1);                    \
    bf16x8 w10 = *(const bf16x8*)(baA + 7 * 2048 + fo0);                    \
    bf16x8 w11 = *(const bf16x8*)(baA + 7 * 2048 + fo1);                    \
    ST3;                                                                    \
    BARX(); LGK0(); PRIO1();                                                \
    MM(acc[4][0], z00, q00); MM(acc[4][0], z01, q01);                       \
    MM(acc[4][1], z00, q10); MM(acc[4][1], z01, q11);                       \
    MM(acc[4][2], z00, q20); MM(acc[4][2], z01, q21);                       \
    MM(acc[4][3], z00, q30); MM(acc[4][3], z01, q31);                       \
    MM(acc[5][0], z10, q00); MM(acc[5][0], z11, q01);                       \
    MM(acc[5][1], z10, q10); MM(acc[5][1], z11, q11);                       \
    MM(acc[5][2], z10, q20); MM(acc[5][2], z11, q21);                       \
    MM(acc[5][3], z10, q30); MM(acc[5][3], z11, q31);                       \
    PRIO0(); BARX();                                                        \
    ST4;                                                                    \
    VMC6(); BARX(); PRIO1();                                                \
    MM(acc[6][0], w00, q00); MM(acc[6][0], w01, q01);                       \
    MM(acc[6][1], w00, q10); MM(acc[6][1], w01, q11);                       \
    MM(acc[6][2], w00, q20); MM(acc[6][2], w01, q21);                       \
    MM(acc[6][3], w00, q30); MM(acc[6][3], w01, q31);                       \
    MM(acc[7][0], w10, q00); MM(acc[7][0], w11, q01);                       \
    MM(acc[7][1], w10, q10); MM(acc[7][1], w11, q11);                       \
    MM(acc[7][2], w10, q20); MM(acc[7][2], w11, q21);                       \
    MM(acc[7][3], w10, q30); MM(acc[7][3], w11, q31);                       \
    PRIO0(); BARX();                                                        \
  }

template <int EPI>
__global__ __launch_bounds__(512, 2) void gemm_bt(
    const u16* __restrict__ A, const u16* __restrict__ Bm, int K,
    const float* __restrict__ bias, const float* __restrict__ resid,
    float* __restrict__ outf,
    u16* __restrict__ qo, u16* __restrict__ ko, u16* __restrict__ vto) {
  // [buf][half][128 rows x 64 k] bf16 = 16KB per half; 64KB A + 64KB B
  __shared__ __align__(16) u16 sA[2][2][8192];
  __shared__ __align__(16) u16 sB[2][2][8192];
  const int tid = threadIdx.x;
  const int wave = tid >> 6, lane = tid & 63;
  const int lrow = lane & 15, quad = lane >> 4;
  const int wm = wave >> 2, wn = wave & 3;  // 2 x 4 wave grid
  const int kmsk = K - 1;                   // K is a power of two here

  // XCD-chunked bijective swizzle (nwg % 8 == 0 for both grids)
  int bid = blockIdx.y * gridDim.x + blockIdx.x;
  const int nwg = gridDim.x * gridDim.y;
  bid = (bid & 7) * (nwg >> 3) + (bid >> 3);
  const int bx = bid % gridDim.x, by = bid / gridDim.x;
  const int m0 = by * 256, n0 = bx * 256;

  // staging source: thread t covers within-half row (t>>3) (+ j*64),
  // k-chunk c = (t&7) ^ (row&7); row&7 == (t>>3)&7 for all (half, round).
  const int rthr = tid >> 3;
  const int cthr = ((tid & 7) ^ (rthr & 7)) * 8;
  const u16* pA = A + (size_t)(m0 + rthr) * K + cthr;
  const u16* pB = Bm + (size_t)(n0 + rthr) * K + cthr;
  const size_t ro1 = (size_t)64 * K;  // round j=1: +64 rows
  const size_t rh = (size_t)128 * K;  // half 1: +128 rows

  // fragment-read per-lane byte offsets (kstep 0/1): row lrow, slot = c^(lrow&7)
  const int fo0 = lrow * 128 + ((quad ^ (lrow & 7)) << 4);
  const int fo1 = lrow * 128 + (((4 + quad) ^ (lrow & 7)) << 4);

  const floatx4 zf = {0.f, 0.f, 0.f, 0.f};
  floatx4 acc[8][4];
#pragma unroll
  for (int i = 0; i < 8; ++i)
#pragma unroll
    for (int j = 0; j < 4; ++j) acc[i][j] = zf;

  // prologue: tile0 (buf0) fully + tile1 (buf1) B0,B1,A0 = 7 halves (14 loads)
  // vmcnt(6) -> tile0 landed (per-wave count + barrier = collective guarantee)
  STGB(0, 0, 0); STGB(0, 1, 0); STGA(0, 0, 0); STGA(0, 1, 0);
  STGB(1, 0, 64); STGB(1, 1, 64); STGA(1, 0, 64);
  VMC6(); BARX();

  const int NIT = K >> 7;  // 2 K-tiles (BK=64) per iteration
#pragma unroll 1
  for (int it = 0; it < NIT; ++it) {
    const int kt1 = it * 128 + 64;   // tile 2i+1 (A1 half staged at p1)
    const int kt2 = it * 128 + 128;  // tile 2i+2 -> buf0 (p2..p5)
    const int kt3 = it * 128 + 192;  // tile 2i+3 -> buf1 (p6..p8 + next p1)
    // trailing iterations wrap k via kmsk; wrapped data is never consumed
    // (tiles >= K/64 are not computed), all addresses stay in-bounds.
    HALF(0, STGA(1, 1, kt1), STGB(0, 0, kt2), STGB(0, 1, kt2), STGA(0, 0, kt2))
    HALF(1, STGA(0, 1, kt2), STGB(1, 0, kt3), STGB(1, 1, kt3), STGA(1, 0, kt3))
  }

  // epilogue — C/D layout: col = lane&15 (n), row = quad*4 + reg (m)
#pragma unroll
  for (int f = 0; f < 8; ++f)
#pragma unroll
    for (int g = 0; g < 4; ++g)
#pragma unroll
      for (int r = 0; r < 4; ++r) {
        int m = m0 + wm * 128 + f * 16 + quad * 4 + r;
        int n = n0 + wn * 64 + g * 16 + lrow;
        float v = acc[f][g][r] + bias[n];
        if (EPI == 0) {
          int b = m >> 11, s = m & (S_ - 1);
          int nh = n / (3 * HD_);
          int rem = n - nh * 3 * HD_;
          int which = rem >> 7, d = rem & (HD_ - 1);
          int bh = b * NH_ + nh;
          if (which == 0)      qo[(bh * S_ + s) * HD_ + d] = f2bf(v * 0.08838834764831845f);
          else if (which == 1) ko[(bh * S_ + s) * HD_ + d] = f2bf(v);
          else                 vto[(bh * HD_ + d) * S_ + s] = f2bf(v);
        } else {
          int idx = m * H_ + n;
          outf[idx] = v + resid[idx];
        }
      }
}

// ---------------- flash attention (causal + alibi) ----------------
// grid: (S/64, B*NH). block: 256 = 4 waves; wave w owns q rows qbase + w*16 .. +15.
// KV tiles of 64 staged in LDS; online softmax; P -> LDS -> A-fragment for PV.
#define SKSTR 136  // 64 x (128+8) bf16
#define SVSTR 72   // 128 x (64+8) bf16
#define SPSTR 72   // 16 x (64+8) bf16 per wave

__global__ __launch_bounds__(256) void attn_kernel(
    const u16* __restrict__ Qb, const u16* __restrict__ Kb,
    const u16* __restrict__ Vt, const float* __restrict__ alibi,
    u16* __restrict__ ctx) {
  __shared__ __align__(16) u16 sK[64 * SKSTR];
  __shared__ __align__(16) u16 sV[128 * SVSTR];
  __shared__ __align__(16) u16 sP[4 * 16 * SPSTR];
  const int tid  = threadIdx.x;
  const int wave = tid >> 6, lane = tid & 63;
  const int lrow = lane & 15, quad = lane >> 4;
  const int qt = blockIdx.x, bh = blockIdx.y;
  const int qbase = qt * 64;
  const int qrow0 = qbase + wave * 16 + quad * 4;

  const floatx4 zf = {0.f, 0.f, 0.f, 0.f};

  // Q fragments: A[m=lane&15][k=quad*8+j], 4 chunks of k=32 cover d=0..127
  bf16x8 aq[4];
  {
    const u16* qptr = Qb + (bh * S_ + qbase + wave * 16 + lrow) * HD_;
#pragma unroll
    for (int kc = 0; kc < 4; ++kc) aq[kc] = *(const bf16x8*)(qptr + kc * 32 + quad * 8);
  }

  floatx4 o[8];
#pragma unroll
  for (int di = 0; di < 8; ++di) o[di] = zf;
  float m_r[4] = {-1e30f, -1e30f, -1e30f, -1e30f};
  float l_r[4] = {0.f, 0.f, 0.f, 0.f};
  u16* sp = &sP[wave * 16 * SPSTR];

  for (int t = 0; t <= qt; ++t) {
    const int kv0 = t * 64;
    __syncthreads();  // previous iteration's LDS reads done
#pragma unroll
    for (int rr = 0; rr < 4; ++rr) {
      int flat = rr * 256 + tid;  // 0..1023
      {
        int row = flat >> 4, c = flat & 15;  // K tile: 64 rows x 16 chunks
        *(uint4*)&sK[row * SKSTR + c * 8] =
            *(const uint4*)&Kb[(bh * S_ + kv0 + row) * HD_ + c * 8];
      }
      {
        int row = flat >> 3, c = flat & 7;   // Vt tile: 128 rows x 8 chunks
        *(uint4*)&sV[row * SVSTR + c * 8] =
            *(const uint4*)&Vt[(bh * HD_ + row) * S_ + kv0 + c * 8];
      }
    }
    __syncthreads();

    // scores: S[q=16][kv=64], Q pre-scaled by 1/sqrt(HD)
    floatx4 sc[4];
#pragma unroll
    for (int ni = 0; ni < 4; ++ni) {
      floatx4 a = zf;
#pragma unroll
      for (int kc = 0; kc < 4; ++kc) {
        bf16x8 bfrag = *(const bf16x8*)&sK[(ni * 16 + lrow) * SKSTR + kc * 32 + quad * 8];
        a = __builtin_amdgcn_mfma_f32_16x16x32_bf16(aq[kc], bfrag, a, 0, 0, 0);
      }
      sc[ni] = a;
    }

    float al[4];
#pragma unroll
    for (int ni = 0; ni < 4; ++ni) al[ni] = alibi[bh * S_ + kv0 + ni * 16 + lrow];
    const bool diag = (t == qt);

    float p[4][4], alpha[4];
#pragma unroll
    for (int r = 0; r < 4; ++r) {
      float mx = -1e30f;
#pragma unroll
      for (int ni = 0; ni < 4; ++ni) {
        float scv = sc[ni][r] + al[ni];
        if (diag && (kv0 + ni * 16 + lrow) > (qrow0 + r)) scv = -1e30f;  // causal mask
        p[ni][r] = scv;
        mx = fmaxf(mx, scv);
      }
#pragma unroll
      for (int off = 1; off < 16; off <<= 1) mx = fmaxf(mx, __shfl_xor(mx, off));
      float mn = fmaxf(m_r[r], mx);
      float a_ = exp2f((m_r[r] - mn) * LOG2E);
      float s_ = 0.f;
#pragma unroll
      for (int ni = 0; ni < 4; ++ni) {
        float pv = exp2f((p[ni][r] - mn) * LOG2E);
        p[ni][r] = pv;
        s_ += pv;
      }
#pragma unroll
      for (int off = 1; off < 16; off <<= 1) s_ += __shfl_xor(s_, off);
      l_r[r] = l_r[r] * a_ + s_;
      m_r[r] = mn;
      alpha[r] = a_;
    }
#pragma unroll
    for (int di = 0; di < 8; ++di)
#pragma unroll
      for (int r = 0; r < 4; ++r) o[di][r] *= alpha[r];

    // P: C-layout -> LDS (bf16) -> A-fragment layout
#pragma unroll
    for (int ni = 0; ni < 4; ++ni)
#pragma unroll
      for (int r = 0; r < 4; ++r)
        sp[(quad * 4 + r) * SPSTR + ni * 16 + lrow] = f2bf(p[ni][r]);
    __syncthreads();

    // PV: O[q=16][d=128] += P[16][64] * Vt[d][kv]
#pragma unroll
    for (int kc = 0; kc < 2; ++kc) {
      bf16x8 afrag = *(const bf16x8*)&sp[lrow * SPSTR + kc * 32 + quad * 8];
#pragma unroll
      for (int di = 0; di < 8; ++di) {
        bf16x8 bfrag = *(const bf16x8*)&sV[(di * 16 + lrow) * SVSTR + kc * 32 + quad * 8];
        o[di] = __builtin_amdgcn_mfma_f32_16x16x32_bf16(afrag, bfrag, o[di], 0, 0, 0);
      }
    }
  }

  // epilogue: ctx[b][q][nh*128 + d] bf16
  const int b = bh >> 5, nh = bh & (NH_ - 1);
#pragma unroll
  for (int di = 0; di < 8; ++di)
#pragma unroll
    for (int r = 0; r < 4; ++r) {
      int q = qrow0 + r;
      float v = o[di][r] / l_r[r];
      ctx[(b * S_ + q) * H_ + nh * HD_ + di * 16 + lrow] = f2bf(v);
    }
}

// ---------------- launch ----------------
extern "C" void kernel_launch(void* const* d_in, const int* in_sizes, int n_in,
                              void* d_out, int out_size, void* d_ws, size_t ws_size,
                              hipStream_t stream) {
  const float* hs    = (const float*)d_in[0];
  const float* resid = (const float*)d_in[1];
  const float* alibi = (const float*)d_in[2];
  // d_in[3] = attention_mask: deterministic causal triu -> applied analytically
  const float* Wqkv  = (const float*)d_in[4];
  const float* bqkv  = (const float*)d_in[5];
  const float* Wd    = (const float*)d_in[6];
  const float* bd    = (const float*)d_in[7];
  float* out = (float*)d_out;

  u16* ws = (u16*)d_ws;
  // layout (elements): [0, 16.7M) hs_bf16 / later ctx_bf16
  //                    [16.7M, 67.1M) Wqkv_bf16 / later Wd_bf16
  //                    [67.1M..) Q, K, Vt (16.7M each)  => 224 MB total
  u16* hs_bf  = ws;
  u16* ctx_bf = ws;                 // alias: hs_bf dead after QKV GEMM
  u16* w_bf   = ws + 16777216;
  u16* Qb     = ws + 67108864;
  u16* Kb     = ws + 83886080;
  u16* Vtb    = ws + 100663296;

  cast_f32_bf16<<<16384, 256, 0, stream>>>(hs, hs_bf, 4194304);
  cast_f32_bf16<<<49152, 256, 0, stream>>>(Wqkv, w_bf, 12582912);
  gemm_bt<0><<<dim3(48, 16), 512, 0, stream>>>(hs_bf, w_bf, 4096, bqkv,
                                               nullptr, nullptr, Qb, Kb, Vtb);
  attn_kernel<<<dim3(32, 64), 256, 0, stream>>>(Qb, Kb, Vtb, alibi, ctx_bf);
  cast_f32_bf16<<<16384, 256, 0, stream>>>(Wd, w_bf, 4194304);
  gemm_bt<1><<<dim3(16, 16), 512, 0, stream>>>(ctx_bf, w_bf, 4096, bd,
                                               resid, out, nullptr, nullptr, nullptr);
}

// Round 3
// 1317.690 us; speedup vs baseline: 1.2204x; 1.0257x over previous
//
#include <hip/hip_runtime.h>

#define B_ 2
#define S_ 2048
#define H_ 4096
#define NH_ 32
#define HD_ 128
#define LOG2E 1.44269504088896340736f

typedef unsigned short u16;
typedef __bf16 bf16x8 __attribute__((ext_vector_type(8)));
typedef float floatx4 __attribute__((ext_vector_type(4)));

__device__ __forceinline__ u16 f2bf(float f) {
  union { float f; unsigned u; } v;
  v.f = f;
  unsigned r = v.u + 0x7FFFu + ((v.u >> 16) & 1u);
  return (u16)(r >> 16);
}

// async global->LDS DMA, 16B per lane; LDS dest = wave-uniform base + lane*16
__device__ __forceinline__ void dma16(const u16* g, u16* l) {
  __builtin_amdgcn_global_load_lds(
      (const __attribute__((address_space(1))) void*)g,
      (__attribute__((address_space(3))) void*)l, 16, 0, 0);
}

// ---------------- cast fp32 -> bf16, vectorized ----------------
__global__ __launch_bounds__(256) void cast_f32_bf16(const float* __restrict__ in,
                                                     u16* __restrict__ out, int n4) {
  int i = blockIdx.x * 256 + threadIdx.x;
  if (i >= n4) return;
  float4 f = reinterpret_cast<const float4*>(in)[i];
  ushort4 o;
  o.x = f2bf(f.x); o.y = f2bf(f.y); o.z = f2bf(f.z); o.w = f2bf(f.w);
  reinterpret_cast<ushort4*>(out)[i] = o;
}

// ---------------- GEMM: C[m][n] = sum_k A[m][k]*B[n][k] (both K-contiguous)
// 256x256 tile, BK=64, 512 threads = 8 waves (2M x 4N), each wave 128x64 out.
// Pipelined 4-region schedule per K-tile (ONE barrier per region):
//   R1: issue x,q,y reads + ST1; MFMA-x (counted lgkmcnt leaves y in flight)
//   R2: issue z,w + ST2; MFMA-y (z,w drain under MFMA)
//   R3: lgkmcnt(0) [WAR fence for ST4] + ST3; MFMA-z
//   R4: ST4; vmcnt(6); barrier; MFMA-w  -- region stays OPEN so the next
//       K-tile's x,q,y reads interleave with MFMA-w (the vmcnt(6)+barrier is
//       exactly the landing guarantee for that buffer).
// Staging via global_load_lds width=16, XOR chunk swizzle (slot = c^(row&7))
// applied to per-lane GLOBAL source and to ds_read address: 0 bank conflicts.
// Trailing prefetches wrap k via (kk & (K-1)): data never consumed, no OOB.
#define MM(d, a_, b_) d = __builtin_amdgcn_mfma_f32_16x16x32_bf16(a_, b_, d, 0, 0, 0)
#define BARX() do { __builtin_amdgcn_s_barrier(); __builtin_amdgcn_sched_barrier(0); } while (0)
#define LGK0() do { asm volatile("s_waitcnt lgkmcnt(0)" ::: "memory"); __builtin_amdgcn_sched_barrier(0); } while (0)
#define VMC6() do { asm volatile("s_waitcnt vmcnt(6)" ::: "memory"); } while (0)
#define PRIO1() __builtin_amdgcn_s_setprio(1)
#define PRIO0() __builtin_amdgcn_s_setprio(0)

// stage one 128x64 half-tile (2 x global_load_lds per thread)
#define STGA(b, h, kk)                                                      \
  do {                                                                      \
    const u16* _g = pA + ((h) ? rh : (size_t)0) + (size_t)((kk) & kmsk);    \
    dma16(_g, &sA[b][h][wave * 512]);                                       \
    dma16(_g + ro1, &sA[b][h][4096 + wave * 512]);                          \
  } while (0)
#define STGB(b, h, kk)                                                      \
  do {                                                                      \
    const u16* _g = pB + ((h) ? rh : (size_t)0) + (size_t)((kk) & kmsk);    \
    dma16(_g, &sB[b][h][wave * 512]);                                       \
    dma16(_g + ro1, &sB[b][h][4096 + wave * 512]);                          \
  } while (0)

// Rotated K-tile body. Region entered OPEN (prev VMC6+BARX passed, prev
// MFMA-w may still be scheduling); exits OPEN after its own MFMA-w.
// WAR audit (single barrier per region):
//  - q drained by counted wait before MFMA-x (R1) => before R1 barrier;
//    ST2 (R2) / ST3 (R3) write sB[b] at least 1-2 barriers later.  OK
//  - x/y/z drained before their MFMAs => before their region barriers;
//    ST4 (R4) writes sA[b][0] after R3 barrier.  OK
//  - w has no use before ST4 issues => explicit LGK0 in R3 forces drain
//    chip-wide before the R3 barrier that precedes ST4.  REQUIRED.
//  - next-tile x',q',y' (issued after R4's VMC6+BARX): their buffer's 8
//    stage-loads are all older than the 6 left outstanding by vmcnt(6).  OK
#define HALFR(b, ST1, ST2, ST3, ST4)                                        \
  {                                                                         \
    const char* baA = (const char*)&sA[b][wm][0];                           \
    const char* baB = (const char*)&sB[b][wn >> 1][(wn & 1) * 4096];        \
    /* R1: x (A rows0-1), q (all B), y (A rows2-3) */                       \
    bf16x8 x00 = *(const bf16x8*)(baA + 0 * 2048 + fo0);                    \
    bf16x8 x01 = *(const bf16x8*)(baA + 0 * 2048 + fo1);                    \
    bf16x8 x10 = *(const bf16x8*)(baA + 1 * 2048 + fo0);                    \
    bf16x8 x11 = *(const bf16x8*)(baA + 1 * 2048 + fo1);                    \
    bf16x8 q00 = *(const bf16x8*)(baB + 0 * 2048 + fo0);                    \
    bf16x8 q01 = *(const bf16x8*)(baB + 0 * 2048 + fo1);                    \
    bf16x8 q10 = *(const bf16x8*)(baB + 1 * 2048 + fo0);                    \
    bf16x8 q11 = *(const bf16x8*)(baB + 1 * 2048 + fo1);                    \
    bf16x8 q20 = *(const bf16x8*)(baB + 2 * 2048 + fo0);                    \
    bf16x8 q21 = *(const bf16x8*)(baB + 2 * 2048 + fo1);                    \
    bf16x8 q30 = *(const bf16x8*)(baB + 3 * 2048 + fo0);                    \
    bf16x8 q31 = *(const bf16x8*)(baB + 3 * 2048 + fo1);                    \
    bf16x8 y00 = *(const bf16x8*)(baA + 2 * 2048 + fo0);                    \
    bf16x8 y01 = *(const bf16x8*)(baA + 2 * 2048 + fo1);                    \
    bf16x8 y10 = *(const bf16x8*)(baA + 3 * 2048 + fo0);                    \
    bf16x8 y11 = *(const bf16x8*)(baA + 3 * 2048 + fo1);                    \
    ST1;                                                                    \
    PRIO1();                                                                \
    MM(acc[0][0], x00, q00); MM(acc[0][0], x01, q01);                       \
    MM(acc[0][1], x00, q10); MM(acc[0][1], x01, q11);                       \
    MM(acc[0][2], x00, q20); MM(acc[0][2], x01, q21);                       \
    MM(acc[0][3], x00, q30); MM(acc[0][3], x01, q31);                       \
    MM(acc[1][0], x10, q00); MM(acc[1][0], x11, q01);                       \
    MM(acc[1][1], x10, q10); MM(acc[1][1], x11, q11);                       \
    MM(acc[1][2], x10, q20); MM(acc[1][2], x11, q21);                       \
    MM(acc[1][3], x10, q30); MM(acc[1][3], x11, q31);                       \
    PRIO0(); BARX();                                                        \
    /* R2: z (A rows4-5), w (A rows6-7) issued; y consumed */               \
    bf16x8 z00 = *(const bf16x8*)(baA + 4 * 2048 + fo0);                    \
    bf16x8 z01 = *(const bf16x8*)(baA + 4 * 2048 + fo1);                    \
    bf16x8 z10 = *(const bf16x8*)(baA + 5 * 2048 + fo0);                    \
    bf16x8 z11 = *(const bf16x8*)(baA + 5 * 2048 + fo1);                    \
    bf16x8 w00 = *(const bf16x8*)(baA + 6 * 2048 + fo0);                    \
    bf16x8 w01 = *(const bf16x8*)(baA + 6 * 2048 + fo1);                    \
    bf16x8 w10 = *(const bf16x8*)(baA + 7 * 2048 + fo0);                    \
    bf16x8 w11 = *(const bf16x8*)(baA + 7 * 2048 + fo1);                    \
    ST2;                                                                    \
    PRIO1();                                                                \
    MM(acc[2][0], y00, q00); MM(acc[2][0], y01, q01);                       \
    MM(acc[2][1], y00, q10); MM(acc[2][1], y01, q11);                       \
    MM(acc[2][2], y00, q20); MM(acc[2][2], y01, q21);                       \
    MM(acc[2][3], y00, q30); MM(acc[2][3], y01, q31);                       \
    MM(acc[3][0], y10, q00); MM(acc[3][0], y11, q01);                       \
    MM(acc[3][1], y10, q10); MM(acc[3][1], y11, q11);                       \
    MM(acc[3][2], y10, q20); MM(acc[3][2], y11, q21);                       \
    MM(acc[3][3], y10, q30); MM(acc[3][3], y11, q31);                       \
    PRIO0(); BARX();                                                        \
    /* R3: full drain (w!) before the barrier that precedes ST4 */          \
    LGK0();                                                                 \
    ST3;                                                                    \
    PRIO1();                                                                \
    MM(acc[4][0], z00, q00); MM(acc[4][0], z01, q01);                       \
    MM(acc[4][1], z00, q10); MM(acc[4][1], z01, q11);                       \
    MM(acc[4][2], z00, q20); MM(acc[4][2], z01, q21);                       \
    MM(acc[4][3], z00, q30); MM(acc[4][3], z01, q31);                       \
    MM(acc[5][0], z10, q00); MM(acc[5][0], z11, q01);                       \
    MM(acc[5][1], z10, q10); MM(acc[5][1], z11, q11);                       \
    MM(acc[5][2], z10, q20); MM(acc[5][2], z11, q21);                       \
    MM(acc[5][3], z10, q30); MM(acc[5][3], z11, q31);                       \
    PRIO0(); BARX();                                                        \
    /* R4: stage, landing fence, MFMA-w; region stays open */               \
    ST4;                                                                    \
    VMC6(); BARX();                                                         \
    PRIO1();                                                                \
    MM(acc[6][0], w00, q00); MM(acc[6][0], w01, q01);                       \
    MM(acc[6][1], w00, q10); MM(acc[6][1], w01, q11);                       \
    MM(acc[6][2], w00, q20); MM(acc[6][2], w01, q21);                       \
    MM(acc[6][3], w00, q30); MM(acc[6][3], w01, q31);                       \
    MM(acc[7][0], w10, q00); MM(acc[7][0], w11, q01);                       \
    MM(acc[7][1], w10, q10); MM(acc[7][1], w11, q11);                       \
    MM(acc[7][2], w10, q20); MM(acc[7][2], w11, q21);                       \
    MM(acc[7][3], w10, q30); MM(acc[7][3], w11, q31);                       \
    PRIO0();                                                                \
  }

template <int EPI>
__global__ __launch_bounds__(512, 2) void gemm_bt(
    const u16* __restrict__ A, const u16* __restrict__ Bm, int K,
    const float* __restrict__ bias, const float* __restrict__ resid,
    float* __restrict__ outf,
    u16* __restrict__ qo, u16* __restrict__ ko, u16* __restrict__ vto) {
  // [buf][half][128 rows x 64 k] bf16 = 16KB per half; 64KB A + 64KB B
  __shared__ __align__(16) u16 sA[2][2][8192];
  __shared__ __align__(16) u16 sB[2][2][8192];
  const int tid = threadIdx.x;
  const int wave = tid >> 6, lane = tid & 63;
  const int lrow = lane & 15, quad = lane >> 4;
  const int wm = wave >> 2, wn = wave & 3;  // 2 x 4 wave grid
  const int kmsk = K - 1;                   // K is a power of two here

  // XCD-chunked bijective swizzle (nwg % 8 == 0 for both grids)
  int bid = blockIdx.y * gridDim.x + blockIdx.x;
  const int nwg = gridDim.x * gridDim.y;
  bid = (bid & 7) * (nwg >> 3) + (bid >> 3);
  const int bx = bid % gridDim.x, by = bid / gridDim.x;
  const int m0 = by * 256, n0 = bx * 256;

  // staging source: thread t covers within-half row (t>>3) (+ j*64),
  // k-chunk c = (t&7) ^ (row&7); row&7 == (t>>3)&7 for all (half, round).
  const int rthr = tid >> 3;
  const int cthr = ((tid & 7) ^ (rthr & 7)) * 8;
  const u16* pA = A + (size_t)(m0 + rthr) * K + cthr;
  const u16* pB = Bm + (size_t)(n0 + rthr) * K + cthr;
  const size_t ro1 = (size_t)64 * K;  // round j=1: +64 rows
  const size_t rh = (size_t)128 * K;  // half 1: +128 rows

  // fragment-read per-lane byte offsets (kstep 0/1): row lrow, slot = c^(lrow&7)
  const int fo0 = lrow * 128 + ((quad ^ (lrow & 7)) << 4);
  const int fo1 = lrow * 128 + (((4 + quad) ^ (lrow & 7)) << 4);

  const floatx4 zf = {0.f, 0.f, 0.f, 0.f};
  floatx4 acc[8][4];
#pragma unroll
  for (int i = 0; i < 8; ++i)
#pragma unroll
    for (int j = 0; j < 4; ++j) acc[i][j] = zf;

  // prologue: tile0 (buf0) fully + tile1 (buf1) B0,B1,A0 = 7 halves (14 loads)
  // vmcnt(6) -> tile0 landed (per-wave count + barrier = collective guarantee)
  STGB(0, 0, 0); STGB(0, 1, 0); STGA(0, 0, 0); STGA(0, 1, 0);
  STGB(1, 0, 64); STGB(1, 1, 64); STGA(1, 0, 64);
  VMC6(); BARX();

  const int NIT = K >> 7;  // 2 K-tiles (BK=64) per iteration
#pragma unroll 1
  for (int it = 0; it < NIT; ++it) {
    const int kt1 = it * 128 + 64;   // tile 2i+1 (A1 half staged at R1)
    const int kt2 = it * 128 + 128;  // tile 2i+2 -> buf0
    const int kt3 = it * 128 + 192;  // tile 2i+3 -> buf1
    // trailing iterations wrap k via kmsk; wrapped data is never consumed
    // (tiles >= K/64 are not computed), all addresses stay in-bounds.
    HALFR(0, STGA(1, 1, kt1), STGB(0, 0, kt2), STGB(0, 1, kt2), STGA(0, 0, kt2))
    HALFR(1, STGA(0, 1, kt2), STGB(1, 0, kt3), STGB(1, 1, kt3), STGA(1, 0, kt3))
  }

  // epilogue — C/D layout: col = lane&15 (n), row = quad*4 + reg (m)
#pragma unroll
  for (int f = 0; f < 8; ++f)
#pragma unroll
    for (int g = 0; g < 4; ++g)
#pragma unroll
      for (int r = 0; r < 4; ++r) {
        int m = m0 + wm * 128 + f * 16 + quad * 4 + r;
        int n = n0 + wn * 64 + g * 16 + lrow;
        float v = acc[f][g][r] + bias[n];
        if (EPI == 0) {
          int b = m >> 11, s = m & (S_ - 1);
          int nh = n / (3 * HD_);
          int rem = n - nh * 3 * HD_;
          int which = rem >> 7, d = rem & (HD_ - 1);
          int bh = b * NH_ + nh;
          if (which == 0)      qo[(bh * S_ + s) * HD_ + d] = f2bf(v * 0.08838834764831845f);
          else if (which == 1) ko[(bh * S_ + s) * HD_ + d] = f2bf(v);
          else                 vto[(bh * HD_ + d) * S_ + s] = f2bf(v);
        } else {
          int idx = m * H_ + n;
          outf[idx] = v + resid[idx];
        }
      }
}

// ---------------- flash attention (causal + alibi) ----------------
// grid: (S/64, B*NH). block: 256 = 4 waves; wave w owns q rows qbase + w*16 .. +15.
// KV tiles of 64 staged in LDS; online softmax; P -> LDS -> A-fragment for PV.
#define SKSTR 136  // 64 x (128+8) bf16
#define SVSTR 72   // 128 x (64+8) bf16
#define SPSTR 72   // 16 x (64+8) bf16 per wave

__global__ __launch_bounds__(256) void attn_kernel(
    const u16* __restrict__ Qb, const u16* __restrict__ Kb,
    const u16* __restrict__ Vt, const float* __restrict__ alibi,
    u16* __restrict__ ctx) {
  __shared__ __align__(16) u16 sK[64 * SKSTR];
  __shared__ __align__(16) u16 sV[128 * SVSTR];
  __shared__ __align__(16) u16 sP[4 * 16 * SPSTR];
  const int tid  = threadIdx.x;
  const int wave = tid >> 6, lane = tid & 63;
  const int lrow = lane & 15, quad = lane >> 4;
  const int qt = blockIdx.x, bh = blockIdx.y;
  const int qbase = qt * 64;
  const int qrow0 = qbase + wave * 16 + quad * 4;

  const floatx4 zf = {0.f, 0.f, 0.f, 0.f};

  // Q fragments: A[m=lane&15][k=quad*8+j], 4 chunks of k=32 cover d=0..127
  bf16x8 aq[4];
  {
    const u16* qptr = Qb + (bh * S_ + qbase + wave * 16 + lrow) * HD_;
#pragma unroll
    for (int kc = 0; kc < 4; ++kc) aq[kc] = *(const bf16x8*)(qptr + kc * 32 + quad * 8);
  }

  floatx4 o[8];
#pragma unroll
  for (int di = 0; di < 8; ++di) o[di] = zf;
  float m_r[4] = {-1e30f, -1e30f, -1e30f, -1e30f};
  float l_r[4] = {0.f, 0.f, 0.f, 0.f};
  u16* sp = &sP[wave * 16 * SPSTR];

  for (int t = 0; t <= qt; ++t) {
    const int kv0 = t * 64;
    __syncthreads();  // previous iteration's LDS reads done
#pragma unroll
    for (int rr = 0; rr < 4; ++rr) {
      int flat = rr * 256 + tid;  // 0..1023
      {
        int row = flat >> 4, c = flat & 15;  // K tile: 64 rows x 16 chunks
        *(uint4*)&sK[row * SKSTR + c * 8] =
            *(const uint4*)&Kb[(bh * S_ + kv0 + row) * HD_ + c * 8];
      }
      {
        int row = flat >> 3, c = flat & 7;   // Vt tile: 128 rows x 8 chunks
        *(uint4*)&sV[row * SVSTR + c * 8] =
            *(const uint4*)&Vt[(bh * HD_ + row) * S_ + kv0 + c * 8];
      }
    }
    __syncthreads();

    // scores: S[q=16][kv=64], Q pre-scaled by 1/sqrt(HD)
    floatx4 sc[4];
#pragma unroll
    for (int ni = 0; ni < 4; ++ni) {
      floatx4 a = zf;
#pragma unroll
      for (int kc = 0; kc < 4; ++kc) {
        bf16x8 bfrag = *(const bf16x8*)&sK[(ni * 16 + lrow) * SKSTR + kc * 32 + quad * 8];
        a = __builtin_amdgcn_mfma_f32_16x16x32_bf16(aq[kc], bfrag, a, 0, 0, 0);
      }
      sc[ni] = a;
    }

    float al[4];
#pragma unroll
    for (int ni = 0; ni < 4; ++ni) al[ni] = alibi[bh * S_ + kv0 + ni * 16 + lrow];
    const bool diag = (t == qt);

    float p[4][4], alpha[4];
#pragma unroll
    for (int r = 0; r < 4; ++r) {
      float mx = -1e30f;
#pragma unroll
      for (int ni = 0; ni < 4; ++ni) {
        float scv = sc[ni][r] + al[ni];
        if (diag && (kv0 + ni * 16 + lrow) > (qrow0 + r)) scv = -1e30f;  // causal mask
        p[ni][r] = scv;
        mx = fmaxf(mx, scv);
      }
#pragma unroll
      for (int off = 1; off < 16; off <<= 1) mx = fmaxf(mx, __shfl_xor(mx, off));
      float mn = fmaxf(m_r[r], mx);
      float a_ = exp2f((m_r[r] - mn) * LOG2E);
      float s_ = 0.f;
#pragma unroll
      for (int ni = 0; ni < 4; ++ni) {
        float pv = exp2f((p[ni][r] - mn) * LOG2E);
        p[ni][r] = pv;
        s_ += pv;
      }
#pragma unroll
      for (int off = 1; off < 16; off <<= 1) s_ += __shfl_xor(s_, off);
      l_r[r] = l_r[r] * a_ + s_;
      m_r[r] = mn;
      alpha[r] = a_;
    }
#pragma unroll
    for (int di = 0; di < 8; ++di)
#pragma unroll
      for (int r = 0; r < 4; ++r) o[di][r] *= alpha[r];

    // P: C-layout -> LDS (bf16) -> A-fragment layout
#pragma unroll
    for (int ni = 0; ni < 4; ++ni)
#pragma unroll
      for (int r = 0; r < 4; ++r)
        sp[(quad * 4 + r) * SPSTR + ni * 16 + lrow] = f2bf(p[ni][r]);
    __syncthreads();

    // PV: O[q=16][d=128] += P[16][64] * Vt[d][kv]
#pragma unroll
    for (int kc = 0; kc < 2; ++kc) {
      bf16x8 afrag = *(const bf16x8*)&sp[lrow * SPSTR + kc * 32 + quad * 8];
#pragma unroll
      for (int di = 0; di < 8; ++di) {
        bf16x8 bfrag = *(const bf16x8*)&sV[(di * 16 + lrow) * SVSTR + kc * 32 + quad * 8];
        o[di] = __builtin_amdgcn_mfma_f32_16x16x32_bf16(afrag, bfrag, o[di], 0, 0, 0);
      }
    }
  }

  // epilogue: ctx[b][q][nh*128 + d] bf16
  const int b = bh >> 5, nh = bh & (NH_ - 1);
#pragma unroll
  for (int di = 0; di < 8; ++di)
#pragma unroll
    for (int r = 0; r < 4; ++r) {
      int q = qrow0 + r;
      float v = o[di][r] / l_r[r];
      ctx[(b * S_ + q) * H_ + nh * HD_ + di * 16 + lrow] = f2bf(v);
    }
}

// ---------------- launch ----------------
extern "C" void kernel_launch(void* const* d_in, const int* in_sizes, int n_in,
                              void* d_out, int out_size, void* d_ws, size_t ws_size,
                              hipStream_t stream) {
  const float* hs    = (const float*)d_in[0];
  const float* resid = (const float*)d_in[1];
  const float* alibi = (const float*)d_in[2];
  // d_in[3] = attention_mask: deterministic causal triu -> applied analytically
  const float* Wqkv  = (const float*)d_in[4];
  const float* bqkv  = (const float*)d_in[5];
  const float* Wd    = (const float*)d_in[6];
  const float* bd    = (const float*)d_in[7];
  float* out = (float*)d_out;

  u16* ws = (u16*)d_ws;
  // layout (elements): [0, 16.7M) hs_bf16 / later ctx_bf16
  //                    [16.7M, 67.1M) Wqkv_bf16 / later Wd_bf16
  //                    [67.1M..) Q, K, Vt (16.7M each)  => 224 MB total
  u16* hs_bf  = ws;
  u16* ctx_bf = ws;                 // alias: hs_bf dead after QKV GEMM
  u16* w_bf   = ws + 16777216;
  u16* Qb     = ws + 67108864;
  u16* Kb     = ws + 83886080;
  u16* Vtb    = ws + 100663296;

  cast_f32_bf16<<<16384, 256, 0, stream>>>(hs, hs_bf, 4194304);
  cast_f32_bf16<<<49152, 256, 0, stream>>>(Wqkv, w_bf, 12582912);
  gemm_bt<0><<<dim3(48, 16), 512, 0, stream>>>(hs_bf, w_bf, 4096, bqkv,
                                               nullptr, nullptr, Qb, Kb, Vtb);
  attn_kernel<<<dim3(32, 64), 256, 0, stream>>>(Qb, Kb, Vtb, alibi, ctx_bf);
  cast_f32_bf16<<<16384, 256, 0, stream>>>(Wd, w_bf, 4194304);
  gemm_bt<1><<<dim3(16, 16), 512, 0, stream>>>(ctx_bf, w_bf, 4096, bd,
                                               resid, out, nullptr, nullptr, nullptr);
}